// Round 11
// baseline (55.764 us; speedup 1.0000x reference)
//
#include <hip/hip_runtime.h>
#include <math.h>

// TopoBrainPhysical fused forward, round 11.
// R10 isolated k2 = 40.4us, LDS-pipe-bound (M streams 18.4KB/element, 4-addr
// reads = 64B/instr). This round: k2 processes E=2 elements/thread with an
// 8-way lane split (4 cellpairs x 2 output-halves):
//   - M traffic per element halves (reads shared by both elements)
//   - 8 distinct addresses/instr -> full 128B LDS width, zero conflicts
//     (stride 580 == 4 mod 32; +12-float half offset keeps it bijective)
//   - accumulators t0[12]+t1[12] = 24 regs -> live ~60, under the ~64 pin
// Reduce: quad_sum over cellpairs (DPP); readout half-partials exchanged via
// one ds_swizzle xor-4 per value. k1: unroll 2 on main loop (latency-bound).

#define PI_F 3.14159265358979323846f

__device__ __forceinline__ float fast_tanh(float v) {
    float e = __expf(2.0f * v);
    return 1.0f - 2.0f * __builtin_amdgcn_rcpf(e + 1.0f);
}

// butterfly sum over the 4 lanes of a quad; all lanes get the total.
__device__ __forceinline__ float quad_sum(float x) {
    x += __int_as_float(__builtin_amdgcn_update_dpp(
             0, __float_as_int(x), 0xB1, 0xF, 0xF, true)); // {1,0,3,2}
    x += __int_as_float(__builtin_amdgcn_update_dpp(
             0, __float_as_int(x), 0x4E, 0xF, 0xF, true)); // {2,3,0,1}
    return x;
}

// add value from lane^4 (ds_swizzle xor mode, offset 0x101F = xor 4, and 0x1F)
__device__ __forceinline__ float xor4_sum(float x) {
    return x + __int_as_float(
        __builtin_amdgcn_ds_swizzle(__float_as_int(x), 0x101F));
}

// ===================== kernel 1 (+ appended setup blocks) =====================
// LDS float layout:
// E1P[24][8]@0 (per k: ew1[0..3][k], eb1[k], pad3)   192
// EW2[24][24]@192   EB2[24]@768   EW3T[3][24]@792   EB3[3]@864  -> 880 total
#define K1_LDS 880
// ws layout: [0, B*20)  per-element {z(4), mc(8), mw(8)}  (AoS)
//            [B*20, +4608) M_cell[8][24][24]   [+4608, +4632) tinit[24]

extern "C" __global__ void __launch_bounds__(256, 2)
topo_k1(const float* __restrict__ x,
        const float* __restrict__ ew1, const float* __restrict__ eb1,
        const float* __restrict__ ew2, const float* __restrict__ eb2,
        const float* __restrict__ ew3, const float* __restrict__ eb3,
        const float* __restrict__ alog, const float* __restrict__ rlog,
        const float* __restrict__ nw2, const float* __restrict__ nb2,
        const float* __restrict__ rw1, const float* __restrict__ rb1,
        float* __restrict__ ws, int B)
{
    const int nb1b = (B + 255) >> 8;

    // ---------------- appended setup blocks: build M_cell and tinit --------
    if ((int)blockIdx.x >= nb1b) {
        const int gid = ((int)blockIdx.x - nb1b) * 256 + (int)threadIdx.x;
        float* M = ws + (size_t)B * 20;
        if (gid < 4608) {
            const int cell = gid / 576, rem = gid - cell * 576;
            const int j = rem / 24, j2 = rem - j * 24;
            float s = 0.0f;
            #pragma unroll
            for (int d = 0; d < 12; ++d)
                s += nw2[j * 12 + d] * rw1[(cell * 12 + d) * 24 + j2];
            M[gid] = s;
        } else if (gid < 4632) {
            const int j2 = gid - 4608;
            float s = rb1[j2];
            for (int i = 0; i < 96; ++i)
                s += nb2[i % 12] * rw1[i * 24 + j2];
            M[4608 + j2] = s;
        }
        return;
    }

    __shared__ float wf[K1_LDS];
    const float4* wq = reinterpret_cast<const float4*>(wf);
    {
        const int tt = threadIdx.x;
        for (int i = tt; i < 24; i += 256) {
            wf[i * 8 + 0] = ew1[i];
            wf[i * 8 + 1] = ew1[24 + i];
            wf[i * 8 + 2] = ew1[48 + i];
            wf[i * 8 + 3] = ew1[72 + i];
            wf[i * 8 + 4] = eb1[i];
        }
        for (int i = tt; i < 576; i += 256) wf[192 + i] = ew2[i];
        for (int i = tt; i < 24;  i += 256) wf[768 + i] = eb2[i];
        for (int i = tt; i < 72;  i += 256) wf[792 + (i % 3) * 24 + (i / 3)] = ew3[i];
        for (int i = tt; i < 3;   i += 256) wf[864 + i] = eb3[i];
    }
    __syncthreads();

    const int b = blockIdx.x * blockDim.x + threadIdx.x;
    if (b >= B) return;

    const float4 xv = *reinterpret_cast<const float4*>(x + (size_t)b * 60 + 56);

    // ---- encoder L1 fused into L2 loop (zt_k is a scalar) ----
    float a2[24];
    #pragma unroll
    for (int c = 0; c < 6; ++c) {
        float4 b4 = wq[192 / 4 + c];
        a2[c*4+0] = b4.x; a2[c*4+1] = b4.y; a2[c*4+2] = b4.z; a2[c*4+3] = b4.w;
    }
    #pragma unroll 2
    for (int k = 0; k < 24; ++k) {
        float4 p  = wq[2 * k];
        float4 p2 = wq[2 * k + 1];
        const float zk = fast_tanh(p2.x + xv.x*p.x + xv.y*p.y + xv.z*p.z + xv.w*p.w);
        const int rr = 48 + k * 6;   // EW2 row k (float4 index)
        float4 r0 = wq[rr+0], r1 = wq[rr+1], r2 = wq[rr+2];
        float4 r3 = wq[rr+3], r4 = wq[rr+4], r5 = wq[rr+5];
        a2[0]+=zk*r0.x; a2[1]+=zk*r0.y; a2[2]+=zk*r0.z; a2[3]+=zk*r0.w;
        a2[4]+=zk*r1.x; a2[5]+=zk*r1.y; a2[6]+=zk*r1.z; a2[7]+=zk*r1.w;
        a2[8]+=zk*r2.x; a2[9]+=zk*r2.y; a2[10]+=zk*r2.z; a2[11]+=zk*r2.w;
        a2[12]+=zk*r3.x; a2[13]+=zk*r3.y; a2[14]+=zk*r3.z; a2[15]+=zk*r3.w;
        a2[16]+=zk*r4.x; a2[17]+=zk*r4.y; a2[18]+=zk*r4.z; a2[19]+=zk*r4.w;
        a2[20]+=zk*r5.x; a2[21]+=zk*r5.y; a2[22]+=zk*r5.z; a2[23]+=zk*r5.w;
    }
    float zt2[24];
    #pragma unroll
    for (int j = 0; j < 24; ++j) zt2[j] = fast_tanh(a2[j]);

    // ---- encoder L3 (24x3, transposed; static tail) ----
    float z0 = wf[864], z1 = wf[865], z2 = wf[866];
    #pragma unroll
    for (int c = 0; c < 6; ++c) {
        float4 v0 = wq[198 + c], v1 = wq[204 + c], v2 = wq[210 + c];
        z0 += zt2[c*4+0]*v0.x + zt2[c*4+1]*v0.y + zt2[c*4+2]*v0.z + zt2[c*4+3]*v0.w;
        z1 += zt2[c*4+0]*v1.x + zt2[c*4+1]*v1.y + zt2[c*4+2]*v1.z + zt2[c*4+3]*v1.w;
        z2 += zt2[c*4+0]*v2.x + zt2[c*4+1]*v2.y + zt2[c*4+2]*v2.z + zt2[c*4+3]*v2.w;
    }

    // ---- normalized adjacency (wave-uniform scalar reads) ----
    float ang[4][4];
    {
        float m = fmaxf(fmaxf(alog[0], alog[1]), fmaxf(alog[2], alog[3]));
        float e0 = __expf(alog[0] - m), e1 = __expf(alog[1] - m);
        float e2 = __expf(alog[2] - m), e3 = __expf(alog[3] - m);
        float s = e0 + e1 + e2 + e3;
        float sm[4] = { e0 / s, e1 / s, e2 / s, e3 / s };
        #pragma unroll
        for (int i = 0; i < 4; ++i) {
            const int jn = (i + 3) & 3, jp = (i + 1) & 3;
            float inv = 1.0f / fmaxf(sm[jn] + sm[jp], 1e-6f);
            #pragma unroll
            for (int j = 0; j < 4; ++j) {
                float adj = (j == jn || j == jp) ? 1.0f : 0.0f;
                ang[i][j] = sm[j] * adj * inv;
            }
        }
    }
    float rad[2][2];
    {
        float m = fmaxf(rlog[0], rlog[1]);
        float f0 = __expf(rlog[0] - m), f1 = __expf(rlog[1] - m);
        float fs = f0 + f1;
        float sm0 = f0 / fs, sm1 = f1 / fs;
        rad[0][0] = 0.0f; rad[0][1] = sm1 / fmaxf(sm1, 1e-6f);
        rad[1][1] = 0.0f; rad[1][0] = sm0 / fmaxf(sm0, 1e-6f);
    }

    // ---- bilinear corners ----
    const float r = 1.0f / (1.0f + __expf(-z0));
    const float p = (z1 + PI_F) / (2.0f * PI_F) * 4.0f;
    const float r0f = truncf(r), p0f = truncf(p);
    const float dr = r - r0f, dp = p - p0f;
    const int r0i = (int)r0f, p0i = (int)p0f;

    const float w0c = (1.0f - dr) * (1.0f - dp);
    const float w1c = (1.0f - dr) * dp;
    const float w2c = dr * (1.0f - dp);
    const float w3c = dr * dp;

    const int ri0 = min(r0i, 1);
    const int ri2 = min(r0i + 1, 1);
    const int pi0 = p0i & 3;
    const int pi1 = (p0i + 1) & 3;

    const int c0 = ri0 * 4 + pi0, c1 = ri0 * 4 + pi1;
    const int c2 = ri2 * 4 + pi0, c3 = ri2 * 4 + pi1;

    float cnt[8], wsum[8];
    #pragma unroll
    for (int n = 0; n < 8; ++n) {
        float cm = 0.0f, cw = 0.0f;
        if (c0 == n && w0c > 0.0f) { cm += 1.0f; cw += w0c; }
        if (c1 == n && w1c > 0.0f) { cm += 1.0f; cw += w1c; }
        if (c2 == n && w2c > 0.0f) { cm += 1.0f; cw += w2c; }
        if (c3 == n && w3c > 0.0f) { cm += 1.0f; cw += w3c; }
        cnt[n] = cm; wsum[n] = cw;
    }
    float mc[8], mw[8];
    #pragma unroll
    for (int n = 0; n < 8; ++n) {
        float ac = cnt[n], aw = wsum[n];
        #pragma unroll
        for (int j = 0; j < 4; ++j) {
            const float g = ang[n >> 1][j];
            ac += g * cnt[2 * j + (n & 1)];
            aw += g * wsum[2 * j + (n & 1)];
        }
        #pragma unroll
        for (int j = 0; j < 2; ++j) {
            const float g = rad[n >> 2][j];
            ac += g * cnt[4 * j + (n & 3)];
            aw += g * wsum[4 * j + (n & 3)];
        }
        mc[n] = ac; mw[n] = aw;
    }

    // ---- AoS store: 20 floats per element ----
    float* wp = ws + (size_t)b * 20;
    float4 v0; v0.x = z0;    v0.y = z1;    v0.z = z2;    v0.w = 0.0f;
    float4 v1; v1.x = mc[0]; v1.y = mc[1]; v1.z = mc[2]; v1.w = mc[3];
    float4 v2; v2.x = mc[4]; v2.y = mc[5]; v2.z = mc[6]; v2.w = mc[7];
    float4 v3; v3.x = mw[0]; v3.y = mw[1]; v3.z = mw[2]; v3.w = mw[3];
    float4 v4; v4.x = mw[4]; v4.y = mw[5]; v4.z = mw[6]; v4.w = mw[7];
    reinterpret_cast<float4*>(wp)[0] = v0;
    reinterpret_cast<float4*>(wp)[1] = v1;
    reinterpret_cast<float4*>(wp)[2] = v2;
    reinterpret_cast<float4*>(wp)[3] = v3;
    reinterpret_cast<float4*>(wp)[4] = v4;
}

// ===================== kernel 2 =====================
// LDS float layout (R10-identical):
// PK[24][8]@0 (nw1[0..3][j], nb1[j], pad3)                 192
// M: 8 cells, stride 580 (24x24 row-major + pad) @192      4640
// tinit[24]@4832  RW2[24][4]@4856  RB2[4]@4952  -> 4956 floats (19.8KB)
// Lane map: cp = tid&3 (cells 2cp, 2cp+1), half = (tid>>2)&1 (outputs
// half*12..+11), slot = tid>>3 -> elements 2*slot, 2*slot+1.
// Bank check (16B reads, offsets mod 32 floats): cellA instr touches
// {0,8,16,24}+{0,12} = {0,8,16,24,12,20,28,4} distinct; cellB likewise.
#define K2_LDS 4956

extern "C" __global__ void __launch_bounds__(256)
topo_k2(const float* __restrict__ ws,
        const float* __restrict__ nw1, const float* __restrict__ nb1,
        const float* __restrict__ rw2, const float* __restrict__ rb2,
        float* __restrict__ out, int B)
{
    __shared__ float wf[K2_LDS];
    const float4* wq = reinterpret_cast<const float4*>(wf);
    {
        const int tt = threadIdx.x;
        const float* Msrc = ws + (size_t)B * 20;
        for (int i = tt; i < 4608; i += 256) {
            const int cell = i / 576, rem = i - cell * 576;
            wf[192 + cell * 580 + rem] = Msrc[i];
        }
        for (int i = tt; i < 24; i += 256) wf[4832 + i] = Msrc[4608 + i];
        for (int i = tt; i < 24; i += 256) {
            wf[i * 8 + 0] = nw1[i];
            wf[i * 8 + 1] = nw1[24 + i];
            wf[i * 8 + 2] = nw1[48 + i];
            wf[i * 8 + 3] = nw1[72 + i];
            wf[i * 8 + 4] = nb1[i];
        }
        for (int i = tt; i < 96; i += 256) wf[4856 + i] = rw2[i];
        for (int i = tt; i < 4;  i += 256) wf[4952 + i] = rb2[i];
    }
    __syncthreads();

    const int tid  = blockIdx.x * blockDim.x + threadIdx.x;
    const int cp   = tid & 3;
    const int half = (tid >> 2) & 1;
    const int slot = tid >> 3;
    const int nP   = (B + 1) >> 1;
    if (slot >= nP) return;
    const int e0  = 2 * slot;
    const int e1s = 2 * slot + 1;
    const int e1  = (e1s < B) ? e1s : (B - 1);

    // per-element state (z + this lane's 2 cells' mc/mw)
    const float* wp0 = ws + (size_t)e0 * 20;
    const float* wp1 = ws + (size_t)e1 * 20;
    const float4 zA = *reinterpret_cast<const float4*>(wp0);
    const float4 zB = *reinterpret_cast<const float4*>(wp1);
    const float2 mc0 = *reinterpret_cast<const float2*>(wp0 + 4 + 2 * cp);
    const float2 mw0 = *reinterpret_cast<const float2*>(wp0 + 12 + 2 * cp);
    const float2 mc1 = *reinterpret_cast<const float2*>(wp1 + 4 + 2 * cp);
    const float2 mw1 = *reinterpret_cast<const float2*>(wp1 + 12 + 2 * cp);

    // M float4 bases: cellA=2cp, cellB=2cp+1; stride 145 float4; half*3 offset
    const int mA = 48 + (2 * cp) * 145 + half * 3;
    const int mB = mA + 145;

    float t0[12], t1[12];
    #pragma unroll
    for (int k = 0; k < 12; ++k) { t0[k] = 0.0f; t1[k] = 0.0f; }

    #pragma unroll 1
    for (int j = 0; j < 24; ++j) {
        float4 pk  = wq[2 * j];
        float4 pk2 = wq[2 * j + 1];
        const float nb = pk2.x, w3 = pk.w;
        const float q0 = zA.x * pk.x + zA.y * pk.y + zA.z * pk.z;
        const float q1 = zB.x * pk.x + zB.y * pk.y + zB.z * pk.z;
        const float hA0 = fast_tanh(nb + mc0.x * q0 + mw0.x * w3);
        const float hB0 = fast_tanh(nb + mc0.y * q0 + mw0.y * w3);
        const float hA1 = fast_tanh(nb + mc1.x * q1 + mw1.x * w3);
        const float hB1 = fast_tanh(nb + mc1.y * q1 + mw1.y * w3);
        const int ra = mA + j * 6, rb = mB + j * 6;
        float4 a0 = wq[ra], a1 = wq[ra + 1], a2 = wq[ra + 2];
        t0[0] += hA0*a0.x; t0[1] += hA0*a0.y; t0[2]  += hA0*a0.z; t0[3]  += hA0*a0.w;
        t0[4] += hA0*a1.x; t0[5] += hA0*a1.y; t0[6]  += hA0*a1.z; t0[7]  += hA0*a1.w;
        t0[8] += hA0*a2.x; t0[9] += hA0*a2.y; t0[10] += hA0*a2.z; t0[11] += hA0*a2.w;
        t1[0] += hA1*a0.x; t1[1] += hA1*a0.y; t1[2]  += hA1*a0.z; t1[3]  += hA1*a0.w;
        t1[4] += hA1*a1.x; t1[5] += hA1*a1.y; t1[6]  += hA1*a1.z; t1[7]  += hA1*a1.w;
        t1[8] += hA1*a2.x; t1[9] += hA1*a2.y; t1[10] += hA1*a2.z; t1[11] += hA1*a2.w;
        float4 b0 = wq[rb], b1 = wq[rb + 1], b2 = wq[rb + 2];
        t0[0] += hB0*b0.x; t0[1] += hB0*b0.y; t0[2]  += hB0*b0.z; t0[3]  += hB0*b0.w;
        t0[4] += hB0*b1.x; t0[5] += hB0*b1.y; t0[6]  += hB0*b1.z; t0[7]  += hB0*b1.w;
        t0[8] += hB0*b2.x; t0[9] += hB0*b2.y; t0[10] += hB0*b2.z; t0[11] += hB0*b2.w;
        t1[0] += hB1*b0.x; t1[1] += hB1*b0.y; t1[2]  += hB1*b0.z; t1[3]  += hB1*b0.w;
        t1[4] += hB1*b1.x; t1[5] += hB1*b1.y; t1[6]  += hB1*b1.z; t1[7]  += hB1*b1.w;
        t1[8] += hB1*b2.x; t1[9] += hB1*b2.y; t1[10] += hB1*b2.z; t1[11] += hB1*b2.w;
    }

    // ---- reduce over cellpairs (quad butterfly); add tinit(half) ----
    #pragma unroll
    for (int k = 0; k < 12; ++k) {
        t0[k] = quad_sum(t0[k]);
        t1[k] = quad_sum(t1[k]);
    }
    #pragma unroll
    for (int c = 0; c < 3; ++c) {
        float4 ti = wq[1208 + half * 3 + c];
        t0[c*4+0] += ti.x; t0[c*4+1] += ti.y; t0[c*4+2] += ti.z; t0[c*4+3] += ti.w;
        t1[c*4+0] += ti.x; t1[c*4+1] += ti.y; t1[c*4+2] += ti.z; t1[c*4+3] += ti.w;
    }

    // ---- readout layer 2: partial over this half's 12 rows ----
    float o00 = 0.0f, o01 = 0.0f, o02 = 0.0f, o03 = 0.0f;
    float o10 = 0.0f, o11 = 0.0f, o12 = 0.0f, o13 = 0.0f;
    #pragma unroll
    for (int k = 0; k < 12; ++k) {
        const float tv0 = fast_tanh(t0[k]);
        const float tv1 = fast_tanh(t1[k]);
        float4 rv = wq[1214 + half * 12 + k];
        o00 += tv0 * rv.x; o01 += tv0 * rv.y; o02 += tv0 * rv.z; o03 += tv0 * rv.w;
        o10 += tv1 * rv.x; o11 += tv1 * rv.y; o12 += tv1 * rv.z; o13 += tv1 * rv.w;
    }
    // exchange half-partials (lane^4) and combine
    o00 = xor4_sum(o00); o01 = xor4_sum(o01); o02 = xor4_sum(o02); o03 = xor4_sum(o03);
    o10 = xor4_sum(o10); o11 = xor4_sum(o11); o12 = xor4_sum(o12); o13 = xor4_sum(o13);

    if ((tid & 7) == 0) {
        float4 ob = wq[1238];
        float4 ovA; ovA.x = o00 + ob.x; ovA.y = o01 + ob.y;
        ovA.z = o02 + ob.z; ovA.w = o03 + ob.w;
        *reinterpret_cast<float4*>(out + (size_t)e0 * 4) = ovA;
        if (e1s < B) {
            float4 ovB; ovB.x = o10 + ob.x; ovB.y = o11 + ob.y;
            ovB.z = o12 + ob.z; ovB.w = o13 + ob.w;
            *reinterpret_cast<float4*>(out + (size_t)e1s * 4) = ovB;
        }
    }
}

// ===================== fallback fused kernel =====================
extern "C" __global__ void __launch_bounds__(256, 2)
topo_fused(const float* __restrict__ x,
           const float* __restrict__ ew1, const float* __restrict__ eb1,
           const float* __restrict__ ew2, const float* __restrict__ eb2,
           const float* __restrict__ ew3, const float* __restrict__ eb3,
           const float* __restrict__ nw1, const float* __restrict__ nb1,
           const float* __restrict__ nw2, const float* __restrict__ nb2,
           const float* __restrict__ alog, const float* __restrict__ rlog,
           const float* __restrict__ rw1, const float* __restrict__ rb1,
           const float* __restrict__ rw2, const float* __restrict__ rb2,
           float* __restrict__ out, int B)
{
    const int b = blockIdx.x * blockDim.x + threadIdx.x;
    if (b >= B) return;

    float ang[4][4];
    {
        float m = fmaxf(fmaxf(alog[0], alog[1]), fmaxf(alog[2], alog[3]));
        float e0 = __expf(alog[0] - m), e1 = __expf(alog[1] - m);
        float e2 = __expf(alog[2] - m), e3 = __expf(alog[3] - m);
        float s = e0 + e1 + e2 + e3;
        float sm[4] = { e0 / s, e1 / s, e2 / s, e3 / s };
        #pragma unroll
        for (int i = 0; i < 4; ++i) {
            const int jn = (i + 3) & 3, jp = (i + 1) & 3;
            float inv = 1.0f / fmaxf(sm[jn] + sm[jp], 1e-6f);
            #pragma unroll
            for (int j = 0; j < 4; ++j) {
                float adj = (j == jn || j == jp) ? 1.0f : 0.0f;
                ang[i][j] = sm[j] * adj * inv;
            }
        }
    }
    float rad[2][2];
    {
        float m = fmaxf(rlog[0], rlog[1]);
        float f0 = __expf(rlog[0] - m), f1 = __expf(rlog[1] - m);
        float fs = f0 + f1;
        float sm0 = f0 / fs, sm1 = f1 / fs;
        rad[0][0] = 0.0f; rad[0][1] = sm1 / fmaxf(sm1, 1e-6f);
        rad[1][1] = 0.0f; rad[1][0] = sm0 / fmaxf(sm0, 1e-6f);
    }

    const float4 xv = *reinterpret_cast<const float4*>(x + (size_t)b * 60 + 56);
    float zt[24];
    #pragma unroll
    for (int j = 0; j < 24; ++j) {
        float a = eb1[j];
        a += xv.x * ew1[j];
        a += xv.y * ew1[24 + j];
        a += xv.z * ew1[48 + j];
        a += xv.w * ew1[72 + j];
        zt[j] = fast_tanh(a);
    }
    float z0 = eb3[0], z1 = eb3[1], z2 = eb3[2];
    #pragma unroll
    for (int j = 0; j < 24; ++j) {
        float a = eb2[j];
        #pragma unroll
        for (int k = 0; k < 24; ++k) a += zt[k] * ew2[k * 24 + j];
        const float z2t = fast_tanh(a);
        z0 += z2t * ew3[j * 3 + 0];
        z1 += z2t * ew3[j * 3 + 1];
        z2 += z2t * ew3[j * 3 + 2];
    }

    const float r = 1.0f / (1.0f + __expf(-z0));
    const float p = (z1 + PI_F) / (2.0f * PI_F) * 4.0f;
    const float r0f = truncf(r), p0f = truncf(p);
    const float dr = r - r0f, dp = p - p0f;
    const int r0i = (int)r0f, p0i = (int)p0f;
    const float w0c = (1.0f - dr) * (1.0f - dp);
    const float w1c = (1.0f - dr) * dp;
    const float w2c = dr * (1.0f - dp);
    const float w3c = dr * dp;
    const int ri0 = min(r0i, 1);
    const int ri2 = min(r0i + 1, 1);
    const int pi0 = p0i & 3;
    const int pi1 = (p0i + 1) & 3;
    const int c0 = ri0 * 4 + pi0, c1 = ri0 * 4 + pi1;
    const int c2 = ri2 * 4 + pi0, c3 = ri2 * 4 + pi1;

    float cnt[8], wsum[8];
    #pragma unroll
    for (int n = 0; n < 8; ++n) {
        float cm = 0.0f, cw = 0.0f;
        if (c0 == n && w0c > 0.0f) { cm += 1.0f; cw += w0c; }
        if (c1 == n && w1c > 0.0f) { cm += 1.0f; cw += w1c; }
        if (c2 == n && w2c > 0.0f) { cm += 1.0f; cw += w2c; }
        if (c3 == n && w3c > 0.0f) { cm += 1.0f; cw += w3c; }
        cnt[n] = cm; wsum[n] = cw;
    }
    float mc[8], mw[8];
    #pragma unroll
    for (int n = 0; n < 8; ++n) {
        float ac = cnt[n], aw = wsum[n];
        #pragma unroll
        for (int j = 0; j < 4; ++j) {
            const float g = ang[n >> 1][j];
            ac += g * cnt[2 * j + (n & 1)];
            aw += g * wsum[2 * j + (n & 1)];
        }
        #pragma unroll
        for (int j = 0; j < 2; ++j) {
            const float g = rad[n >> 2][j];
            ac += g * cnt[4 * j + (n & 3)];
            aw += g * wsum[4 * j + (n & 3)];
        }
        mc[n] = ac; mw[n] = aw;
    }

    float t[24];
    #pragma unroll
    for (int j = 0; j < 24; ++j) t[j] = rb1[j];
    #pragma unroll
    for (int n = 0; n < 8; ++n) {
        const float f0 = mc[n] * z0, f1 = mc[n] * z1, f2 = mc[n] * z2;
        float ho[12];
        #pragma unroll
        for (int d = 0; d < 12; ++d) ho[d] = nb2[d];
        #pragma unroll
        for (int j = 0; j < 24; ++j) {
            const float hj = fast_tanh(nb1[j] + f0 * nw1[j] + f1 * nw1[24 + j]
                                       + f2 * nw1[48 + j] + mw[n] * nw1[72 + j]);
            #pragma unroll
            for (int d = 0; d < 12; ++d) ho[d] += hj * nw2[j * 12 + d];
        }
        #pragma unroll
        for (int d = 0; d < 12; ++d) {
            const int rbase = (n * 12 + d) * 24;
            #pragma unroll
            for (int j2 = 0; j2 < 24; ++j2) t[j2] += ho[d] * rw1[rbase + j2];
        }
    }

    float o0 = rb2[0], o1 = rb2[1], o2 = rb2[2], o3 = rb2[3];
    #pragma unroll
    for (int j = 0; j < 24; ++j) {
        const float tt = fast_tanh(t[j]);
        o0 += tt * rw2[j * 4 + 0];
        o1 += tt * rw2[j * 4 + 1];
        o2 += tt * rw2[j * 4 + 2];
        o3 += tt * rw2[j * 4 + 3];
    }
    float4 ov; ov.x = o0; ov.y = o1; ov.z = o2; ov.w = o3;
    *reinterpret_cast<float4*>(out + (size_t)b * 4) = ov;
}

extern "C" void kernel_launch(void* const* d_in, const int* in_sizes, int n_in,
                              void* d_out, int out_size, void* d_ws, size_t ws_size,
                              hipStream_t stream) {
    const float* x    = (const float*)d_in[0];
    const float* ew1  = (const float*)d_in[1];
    const float* eb1  = (const float*)d_in[2];
    const float* ew2  = (const float*)d_in[3];
    const float* eb2  = (const float*)d_in[4];
    const float* ew3  = (const float*)d_in[5];
    const float* eb3  = (const float*)d_in[6];
    const float* nw1  = (const float*)d_in[7];
    const float* nb1  = (const float*)d_in[8];
    const float* nw2  = (const float*)d_in[9];
    const float* nb2  = (const float*)d_in[10];
    const float* alog = (const float*)d_in[11];
    const float* rlog = (const float*)d_in[12];
    const float* rw1  = (const float*)d_in[13];
    const float* rb1  = (const float*)d_in[14];
    const float* rw2  = (const float*)d_in[15];
    const float* rb2  = (const float*)d_in[16];
    float* out = (float*)d_out;

    const int B = in_sizes[0] / 60;   // x is (B, 15, 4)
    const size_t ws_needed = ((size_t)B * 20 + 4632) * sizeof(float);

    if (ws_size >= ws_needed) {
        float* ws = (float*)d_ws;
        const int nb1b = (B + 255) / 256;
        const int g1 = nb1b + 19;                 // + setup blocks (4632 entries)
        topo_k1<<<g1, 256, 0, stream>>>(x, ew1, eb1, ew2, eb2, ew3, eb3,
                                        alog, rlog, nw2, nb2, rw1, rb1, ws, B);
        const long long nP = ((long long)B + 1) / 2;
        const long long tot2 = nP * 8;
        const int g2 = (int)((tot2 + 255) / 256);
        topo_k2<<<g2, 256, 0, stream>>>(ws, nw1, nb1, rw2, rb2, out, B);
    } else {
        const int g = (B + 255) / 256;
        topo_fused<<<g, 256, 0, stream>>>(
            x, ew1, eb1, ew2, eb2, ew3, eb3, nw1, nb1, nw2, nb2,
            alog, rlog, rw1, rb1, rw2, rb2, out, B);
    }
}

// Round 12
// 50.215 us; speedup vs baseline: 1.1105x; 1.1105x over previous
//
#include <hip/hip_runtime.h>
#include <math.h>

// TopoBrainPhysical fused forward, round 12: PACKED FP32 (v_pk_fma_f32).
// R11 showed k2 VALU-issue-bound (VALUBusy 74%, VGPR 32, no spill, no
// conflicts). gfx950 has dual-pipe fp32: v_pk_fma_f32 = 2 FMA/instr.
// This round packs the dominant FMA chains as ext_vector float2:
//  - k2 t-accum: 48 -> 24 instr/iter; tanh pairs packed; q packed
//  - k1 encoder-L2 accum: 24 -> 12 instr/iter
// M is built in fp64 in the setup blocks (restore rounding margin; R10's
// fusion moved absmax 1.95e-3 -> 4.88e-3 vs threshold 5.98e-3).

#define PI_F 3.14159265358979323846f

typedef float f32x2 __attribute__((ext_vector_type(2)));

__device__ __forceinline__ f32x2 b2(float v) { f32x2 r; r.x = v; r.y = v; return r; }
__device__ __forceinline__ f32x2 pkfma(f32x2 a, f32x2 b, f32x2 c) {
    return __builtin_elementwise_fma(a, b, c);
}

__device__ __forceinline__ float fast_tanh(float v) {
    float e = __expf(2.0f * v);
    return 1.0f - 2.0f * __builtin_amdgcn_rcpf(e + 1.0f);
}

// two tanh at once; exp/rcp scalar (no packed trans), rest packed
__device__ __forceinline__ f32x2 tanh2(f32x2 v) {
    f32x2 e; e.x = __expf(2.0f * v.x); e.y = __expf(2.0f * v.y);
    f32x2 ep = e + b2(1.0f);
    f32x2 r; r.x = __builtin_amdgcn_rcpf(ep.x); r.y = __builtin_amdgcn_rcpf(ep.y);
    return pkfma(b2(-2.0f), r, b2(1.0f));
}

// butterfly sum over the 4 lanes of a quad; all lanes get the total.
__device__ __forceinline__ float quad_sum(float x) {
    x += __int_as_float(__builtin_amdgcn_update_dpp(
             0, __float_as_int(x), 0xB1, 0xF, 0xF, true)); // {1,0,3,2}
    x += __int_as_float(__builtin_amdgcn_update_dpp(
             0, __float_as_int(x), 0x4E, 0xF, 0xF, true)); // {2,3,0,1}
    return x;
}

// add value from lane^4 (ds_swizzle xor mode)
__device__ __forceinline__ float xor4_sum(float x) {
    return x + __int_as_float(
        __builtin_amdgcn_ds_swizzle(__float_as_int(x), 0x101F));
}

// ===================== kernel 1 (+ appended setup blocks) =====================
// LDS float layout:
// E1P[24][8]@0 (per k: ew1[0..3][k], eb1[k], pad3)   192
// EW2[24][24]@192   EB2[24]@768   EW3T[3][24]@792   EB3[3]@864  -> 880 total
#define K1_LDS 880
// ws layout: [0, B*20)  per-element {z(4), mc(8), mw(8)}  (AoS)
//            [B*20, +4608) M_cell[8][24][24]   [+4608, +4632) tinit[24]

extern "C" __global__ void __launch_bounds__(256, 2)
topo_k1(const float* __restrict__ x,
        const float* __restrict__ ew1, const float* __restrict__ eb1,
        const float* __restrict__ ew2, const float* __restrict__ eb2,
        const float* __restrict__ ew3, const float* __restrict__ eb3,
        const float* __restrict__ alog, const float* __restrict__ rlog,
        const float* __restrict__ nw2, const float* __restrict__ nb2,
        const float* __restrict__ rw1, const float* __restrict__ rb1,
        float* __restrict__ ws, int B)
{
    const int nb1b = (B + 255) >> 8;

    // ---------------- appended setup blocks: build M_cell and tinit (fp64) --
    if ((int)blockIdx.x >= nb1b) {
        const int gid = ((int)blockIdx.x - nb1b) * 256 + (int)threadIdx.x;
        float* M = ws + (size_t)B * 20;
        if (gid < 4608) {
            const int cell = gid / 576, rem = gid - cell * 576;
            const int j = rem / 24, j2 = rem - j * 24;
            double s = 0.0;
            #pragma unroll
            for (int d = 0; d < 12; ++d)
                s += (double)nw2[j * 12 + d] * (double)rw1[(cell * 12 + d) * 24 + j2];
            M[gid] = (float)s;
        } else if (gid < 4632) {
            const int j2 = gid - 4608;
            double s = (double)rb1[j2];
            for (int i = 0; i < 96; ++i)
                s += (double)nb2[i % 12] * (double)rw1[i * 24 + j2];
            M[4608 + j2] = (float)s;
        }
        return;
    }

    __shared__ float wf[K1_LDS];
    const float4* wq = reinterpret_cast<const float4*>(wf);
    {
        const int tt = threadIdx.x;
        for (int i = tt; i < 24; i += 256) {
            wf[i * 8 + 0] = ew1[i];
            wf[i * 8 + 1] = ew1[24 + i];
            wf[i * 8 + 2] = ew1[48 + i];
            wf[i * 8 + 3] = ew1[72 + i];
            wf[i * 8 + 4] = eb1[i];
        }
        for (int i = tt; i < 576; i += 256) wf[192 + i] = ew2[i];
        for (int i = tt; i < 24;  i += 256) wf[768 + i] = eb2[i];
        for (int i = tt; i < 72;  i += 256) wf[792 + (i % 3) * 24 + (i / 3)] = ew3[i];
        for (int i = tt; i < 3;   i += 256) wf[864 + i] = eb3[i];
    }
    __syncthreads();

    const int b = blockIdx.x * blockDim.x + threadIdx.x;
    if (b >= B) return;

    const float4 xv = *reinterpret_cast<const float4*>(x + (size_t)b * 60 + 56);

    // ---- encoder L1 fused into L2 loop; a2 accumulated PACKED ----
    f32x2 A2[12];
    #pragma unroll
    for (int c = 0; c < 6; ++c) {
        float4 b4 = wq[192 / 4 + c];
        A2[c*2+0].x = b4.x; A2[c*2+0].y = b4.y;
        A2[c*2+1].x = b4.z; A2[c*2+1].y = b4.w;
    }
    #pragma unroll 2
    for (int k = 0; k < 24; ++k) {
        float4 p  = wq[2 * k];
        float4 p2 = wq[2 * k + 1];
        const float zk = fast_tanh(p2.x + xv.x*p.x + xv.y*p.y + xv.z*p.z + xv.w*p.w);
        const f32x2 zk2 = b2(zk);
        const int rr = 48 + k * 6;   // EW2 row k (float4 index)
        #pragma unroll
        for (int c = 0; c < 6; ++c) {
            float4 rv = wq[rr + c];
            f32x2 r01; r01.x = rv.x; r01.y = rv.y;
            f32x2 r23; r23.x = rv.z; r23.y = rv.w;
            A2[c*2+0] = pkfma(zk2, r01, A2[c*2+0]);
            A2[c*2+1] = pkfma(zk2, r23, A2[c*2+1]);
        }
    }
    float zt2[24];
    #pragma unroll
    for (int j = 0; j < 24; ++j)
        zt2[j] = fast_tanh((j & 1) ? A2[j >> 1].y : A2[j >> 1].x);

    // ---- encoder L3 (24x3, transposed; static tail) ----
    float z0 = wf[864], z1 = wf[865], z2 = wf[866];
    #pragma unroll
    for (int c = 0; c < 6; ++c) {
        float4 v0 = wq[198 + c], v1 = wq[204 + c], v2 = wq[210 + c];
        z0 += zt2[c*4+0]*v0.x + zt2[c*4+1]*v0.y + zt2[c*4+2]*v0.z + zt2[c*4+3]*v0.w;
        z1 += zt2[c*4+0]*v1.x + zt2[c*4+1]*v1.y + zt2[c*4+2]*v1.z + zt2[c*4+3]*v1.w;
        z2 += zt2[c*4+0]*v2.x + zt2[c*4+1]*v2.y + zt2[c*4+2]*v2.z + zt2[c*4+3]*v2.w;
    }

    // ---- normalized adjacency (wave-uniform scalar reads) ----
    float ang[4][4];
    {
        float m = fmaxf(fmaxf(alog[0], alog[1]), fmaxf(alog[2], alog[3]));
        float e0 = __expf(alog[0] - m), e1 = __expf(alog[1] - m);
        float e2 = __expf(alog[2] - m), e3 = __expf(alog[3] - m);
        float s = e0 + e1 + e2 + e3;
        float sm[4] = { e0 / s, e1 / s, e2 / s, e3 / s };
        #pragma unroll
        for (int i = 0; i < 4; ++i) {
            const int jn = (i + 3) & 3, jp = (i + 1) & 3;
            float inv = 1.0f / fmaxf(sm[jn] + sm[jp], 1e-6f);
            #pragma unroll
            for (int j = 0; j < 4; ++j) {
                float adj = (j == jn || j == jp) ? 1.0f : 0.0f;
                ang[i][j] = sm[j] * adj * inv;
            }
        }
    }
    float rad[2][2];
    {
        float m = fmaxf(rlog[0], rlog[1]);
        float f0 = __expf(rlog[0] - m), f1 = __expf(rlog[1] - m);
        float fs = f0 + f1;
        float sm0 = f0 / fs, sm1 = f1 / fs;
        rad[0][0] = 0.0f; rad[0][1] = sm1 / fmaxf(sm1, 1e-6f);
        rad[1][1] = 0.0f; rad[1][0] = sm0 / fmaxf(sm0, 1e-6f);
    }

    // ---- bilinear corners ----
    const float r = 1.0f / (1.0f + __expf(-z0));
    const float p = (z1 + PI_F) / (2.0f * PI_F) * 4.0f;
    const float r0f = truncf(r), p0f = truncf(p);
    const float dr = r - r0f, dp = p - p0f;
    const int r0i = (int)r0f, p0i = (int)p0f;

    const float w0c = (1.0f - dr) * (1.0f - dp);
    const float w1c = (1.0f - dr) * dp;
    const float w2c = dr * (1.0f - dp);
    const float w3c = dr * dp;

    const int ri0 = min(r0i, 1);
    const int ri2 = min(r0i + 1, 1);
    const int pi0 = p0i & 3;
    const int pi1 = (p0i + 1) & 3;

    const int c0 = ri0 * 4 + pi0, c1 = ri0 * 4 + pi1;
    const int c2 = ri2 * 4 + pi0, c3 = ri2 * 4 + pi1;

    float cnt[8], wsum[8];
    #pragma unroll
    for (int n = 0; n < 8; ++n) {
        float cm = 0.0f, cw = 0.0f;
        if (c0 == n && w0c > 0.0f) { cm += 1.0f; cw += w0c; }
        if (c1 == n && w1c > 0.0f) { cm += 1.0f; cw += w1c; }
        if (c2 == n && w2c > 0.0f) { cm += 1.0f; cw += w2c; }
        if (c3 == n && w3c > 0.0f) { cm += 1.0f; cw += w3c; }
        cnt[n] = cm; wsum[n] = cw;
    }
    float mc[8], mw[8];
    #pragma unroll
    for (int n = 0; n < 8; ++n) {
        float ac = cnt[n], aw = wsum[n];
        #pragma unroll
        for (int j = 0; j < 4; ++j) {
            const float g = ang[n >> 1][j];
            ac += g * cnt[2 * j + (n & 1)];
            aw += g * wsum[2 * j + (n & 1)];
        }
        #pragma unroll
        for (int j = 0; j < 2; ++j) {
            const float g = rad[n >> 2][j];
            ac += g * cnt[4 * j + (n & 3)];
            aw += g * wsum[4 * j + (n & 3)];
        }
        mc[n] = ac; mw[n] = aw;
    }

    // ---- AoS store: 20 floats per element ----
    float* wp = ws + (size_t)b * 20;
    float4 v0; v0.x = z0;    v0.y = z1;    v0.z = z2;    v0.w = 0.0f;
    float4 v1; v1.x = mc[0]; v1.y = mc[1]; v1.z = mc[2]; v1.w = mc[3];
    float4 v2; v2.x = mc[4]; v2.y = mc[5]; v2.z = mc[6]; v2.w = mc[7];
    float4 v3; v3.x = mw[0]; v3.y = mw[1]; v3.z = mw[2]; v3.w = mw[3];
    float4 v4; v4.x = mw[4]; v4.y = mw[5]; v4.z = mw[6]; v4.w = mw[7];
    reinterpret_cast<float4*>(wp)[0] = v0;
    reinterpret_cast<float4*>(wp)[1] = v1;
    reinterpret_cast<float4*>(wp)[2] = v2;
    reinterpret_cast<float4*>(wp)[3] = v3;
    reinterpret_cast<float4*>(wp)[4] = v4;
}

// ===================== kernel 2 =====================
// LDS float layout (R10/R11-identical):
// PK[24][8]@0 (nw1[0..3][j], nb1[j], pad3)                 192
// M: 8 cells, stride 580 (24x24 row-major + pad) @192      4640
// tinit[24]@4832  RW2[24][4]@4856  RB2[4]@4952  -> 4956 floats (19.8KB)
// Lane map: cp = tid&3 (cells 2cp, 2cp+1), half = (tid>>2)&1, slot = tid>>3
// -> elements 2*slot, 2*slot+1.
#define K2_LDS 4956

extern "C" __global__ void __launch_bounds__(256)
topo_k2(const float* __restrict__ ws,
        const float* __restrict__ nw1, const float* __restrict__ nb1,
        const float* __restrict__ rw2, const float* __restrict__ rb2,
        float* __restrict__ out, int B)
{
    __shared__ float wf[K2_LDS];
    const float4* wq = reinterpret_cast<const float4*>(wf);
    {
        const int tt = threadIdx.x;
        const float* Msrc = ws + (size_t)B * 20;
        for (int i = tt; i < 4608; i += 256) {
            const int cell = i / 576, rem = i - cell * 576;
            wf[192 + cell * 580 + rem] = Msrc[i];
        }
        for (int i = tt; i < 24; i += 256) wf[4832 + i] = Msrc[4608 + i];
        for (int i = tt; i < 24; i += 256) {
            wf[i * 8 + 0] = nw1[i];
            wf[i * 8 + 1] = nw1[24 + i];
            wf[i * 8 + 2] = nw1[48 + i];
            wf[i * 8 + 3] = nw1[72 + i];
            wf[i * 8 + 4] = nb1[i];
        }
        for (int i = tt; i < 96; i += 256) wf[4856 + i] = rw2[i];
        for (int i = tt; i < 4;  i += 256) wf[4952 + i] = rb2[i];
    }
    __syncthreads();

    const int tid  = blockIdx.x * blockDim.x + threadIdx.x;
    const int cp   = tid & 3;
    const int half = (tid >> 2) & 1;
    const int slot = tid >> 3;
    const int nP   = (B + 1) >> 1;
    if (slot >= nP) return;
    const int e0  = 2 * slot;
    const int e1s = 2 * slot + 1;
    const int e1  = (e1s < B) ? e1s : (B - 1);

    // per-element state (z + this lane's 2 cells' mc/mw), packed across elems
    const float* wp0 = ws + (size_t)e0 * 20;
    const float* wp1 = ws + (size_t)e1 * 20;
    const float4 zA4 = *reinterpret_cast<const float4*>(wp0);
    const float4 zB4 = *reinterpret_cast<const float4*>(wp1);
    const float2 mc0 = *reinterpret_cast<const float2*>(wp0 + 4 + 2 * cp);
    const float2 mw0 = *reinterpret_cast<const float2*>(wp0 + 12 + 2 * cp);
    const float2 mc1 = *reinterpret_cast<const float2*>(wp1 + 4 + 2 * cp);
    const float2 mw1 = *reinterpret_cast<const float2*>(wp1 + 12 + 2 * cp);

    f32x2 ZX; ZX.x = zA4.x; ZX.y = zB4.x;
    f32x2 ZY; ZY.x = zA4.y; ZY.y = zB4.y;
    f32x2 ZZ; ZZ.x = zA4.z; ZZ.y = zB4.z;
    f32x2 MCA; MCA.x = mc0.x; MCA.y = mc1.x;   // cell A, elems {0,1}
    f32x2 MCB; MCB.x = mc0.y; MCB.y = mc1.y;   // cell B
    f32x2 MWA; MWA.x = mw0.x; MWA.y = mw1.x;
    f32x2 MWB; MWB.x = mw0.y; MWB.y = mw1.y;

    // M float4 bases: cellA=2cp, cellB=2cp+1; stride 145 float4; half*3 offset
    const int mA = 48 + (2 * cp) * 145 + half * 3;
    const int mB = mA + 145;

    f32x2 T0[6], T1[6];   // 12 outputs each, packed; T0=elem0, T1=elem1
    #pragma unroll
    for (int k = 0; k < 6; ++k) { T0[k] = b2(0.0f); T1[k] = b2(0.0f); }

    #pragma unroll 1
    for (int j = 0; j < 24; ++j) {
        float4 pk  = wq[2 * j];
        float4 pk2 = wq[2 * j + 1];
        // q for both elements (packed)
        f32x2 Q = ZX * b2(pk.x);
        Q = pkfma(ZY, b2(pk.y), Q);
        Q = pkfma(ZZ, b2(pk.z), Q);
        // h inputs per cell, packed across elements
        f32x2 baseA = pkfma(MWA, b2(pk.w), b2(pk2.x));
        f32x2 baseB = pkfma(MWB, b2(pk.w), b2(pk2.x));
        f32x2 HA = tanh2(pkfma(MCA, Q, baseA));   // {h(e0,cA), h(e1,cA)}
        f32x2 HB = tanh2(pkfma(MCB, Q, baseB));

        const int ra = mA + j * 6, rb = mB + j * 6;
        float4 a0 = wq[ra], a1 = wq[ra + 1], a2v = wq[ra + 2];
        float4 bb0 = wq[rb], bb1 = wq[rb + 1], bb2 = wq[rb + 2];
        f32x2 A0; A0.x = a0.x;  A0.y = a0.y;
        f32x2 A1; A1.x = a0.z;  A1.y = a0.w;
        f32x2 A2; A2.x = a1.x;  A2.y = a1.y;
        f32x2 A3; A3.x = a1.z;  A3.y = a1.w;
        f32x2 A4; A4.x = a2v.x; A4.y = a2v.y;
        f32x2 A5; A5.x = a2v.z; A5.y = a2v.w;
        f32x2 B0; B0.x = bb0.x; B0.y = bb0.y;
        f32x2 B1; B1.x = bb0.z; B1.y = bb0.w;
        f32x2 B2; B2.x = bb1.x; B2.y = bb1.y;
        f32x2 B3; B3.x = bb1.z; B3.y = bb1.w;
        f32x2 B4; B4.x = bb2.x; B4.y = bb2.y;
        f32x2 B5; B5.x = bb2.z; B5.y = bb2.w;

        const f32x2 hA0 = b2(HA.x), hA1 = b2(HA.y);
        const f32x2 hB0 = b2(HB.x), hB1 = b2(HB.y);
        T0[0] = pkfma(hA0, A0, T0[0]); T0[1] = pkfma(hA0, A1, T0[1]);
        T0[2] = pkfma(hA0, A2, T0[2]); T0[3] = pkfma(hA0, A3, T0[3]);
        T0[4] = pkfma(hA0, A4, T0[4]); T0[5] = pkfma(hA0, A5, T0[5]);
        T1[0] = pkfma(hA1, A0, T1[0]); T1[1] = pkfma(hA1, A1, T1[1]);
        T1[2] = pkfma(hA1, A2, T1[2]); T1[3] = pkfma(hA1, A3, T1[3]);
        T1[4] = pkfma(hA1, A4, T1[4]); T1[5] = pkfma(hA1, A5, T1[5]);
        T0[0] = pkfma(hB0, B0, T0[0]); T0[1] = pkfma(hB0, B1, T0[1]);
        T0[2] = pkfma(hB0, B2, T0[2]); T0[3] = pkfma(hB0, B3, T0[3]);
        T0[4] = pkfma(hB0, B4, T0[4]); T0[5] = pkfma(hB0, B5, T0[5]);
        T1[0] = pkfma(hB1, B0, T1[0]); T1[1] = pkfma(hB1, B1, T1[1]);
        T1[2] = pkfma(hB1, B2, T1[2]); T1[3] = pkfma(hB1, B3, T1[3]);
        T1[4] = pkfma(hB1, B4, T1[4]); T1[5] = pkfma(hB1, B5, T1[5]);
    }

    // unpack to scalars (static indices) and reuse the R11 tail
    float t0[12], t1[12];
    #pragma unroll
    for (int k = 0; k < 12; ++k) {
        t0[k] = (k & 1) ? T0[k >> 1].y : T0[k >> 1].x;
        t1[k] = (k & 1) ? T1[k >> 1].y : T1[k >> 1].x;
    }

    // ---- reduce over cellpairs (quad butterfly); add tinit(half) ----
    #pragma unroll
    for (int k = 0; k < 12; ++k) {
        t0[k] = quad_sum(t0[k]);
        t1[k] = quad_sum(t1[k]);
    }
    #pragma unroll
    for (int c = 0; c < 3; ++c) {
        float4 ti = wq[1208 + half * 3 + c];
        t0[c*4+0] += ti.x; t0[c*4+1] += ti.y; t0[c*4+2] += ti.z; t0[c*4+3] += ti.w;
        t1[c*4+0] += ti.x; t1[c*4+1] += ti.y; t1[c*4+2] += ti.z; t1[c*4+3] += ti.w;
    }

    // ---- readout layer 2: partial over this half's 12 rows ----
    float o00 = 0.0f, o01 = 0.0f, o02 = 0.0f, o03 = 0.0f;
    float o10 = 0.0f, o11 = 0.0f, o12 = 0.0f, o13 = 0.0f;
    #pragma unroll
    for (int k = 0; k < 12; ++k) {
        const float tv0 = fast_tanh(t0[k]);
        const float tv1 = fast_tanh(t1[k]);
        float4 rv = wq[1214 + half * 12 + k];
        o00 += tv0 * rv.x; o01 += tv0 * rv.y; o02 += tv0 * rv.z; o03 += tv0 * rv.w;
        o10 += tv1 * rv.x; o11 += tv1 * rv.y; o12 += tv1 * rv.z; o13 += tv1 * rv.w;
    }
    // exchange half-partials (lane^4) and combine
    o00 = xor4_sum(o00); o01 = xor4_sum(o01); o02 = xor4_sum(o02); o03 = xor4_sum(o03);
    o10 = xor4_sum(o10); o11 = xor4_sum(o11); o12 = xor4_sum(o12); o13 = xor4_sum(o13);

    if ((tid & 7) == 0) {
        float4 ob = wq[1238];
        float4 ovA; ovA.x = o00 + ob.x; ovA.y = o01 + ob.y;
        ovA.z = o02 + ob.z; ovA.w = o03 + ob.w;
        *reinterpret_cast<float4*>(out + (size_t)e0 * 4) = ovA;
        if (e1s < B) {
            float4 ovB; ovB.x = o10 + ob.x; ovB.y = o11 + ob.y;
            ovB.z = o12 + ob.z; ovB.w = o13 + ob.w;
            *reinterpret_cast<float4*>(out + (size_t)e1s * 4) = ovB;
        }
    }
}

// ===================== fallback fused kernel =====================
extern "C" __global__ void __launch_bounds__(256, 2)
topo_fused(const float* __restrict__ x,
           const float* __restrict__ ew1, const float* __restrict__ eb1,
           const float* __restrict__ ew2, const float* __restrict__ eb2,
           const float* __restrict__ ew3, const float* __restrict__ eb3,
           const float* __restrict__ nw1, const float* __restrict__ nb1,
           const float* __restrict__ nw2, const float* __restrict__ nb2,
           const float* __restrict__ alog, const float* __restrict__ rlog,
           const float* __restrict__ rw1, const float* __restrict__ rb1,
           const float* __restrict__ rw2, const float* __restrict__ rb2,
           float* __restrict__ out, int B)
{
    const int b = blockIdx.x * blockDim.x + threadIdx.x;
    if (b >= B) return;

    float ang[4][4];
    {
        float m = fmaxf(fmaxf(alog[0], alog[1]), fmaxf(alog[2], alog[3]));
        float e0 = __expf(alog[0] - m), e1 = __expf(alog[1] - m);
        float e2 = __expf(alog[2] - m), e3 = __expf(alog[3] - m);
        float s = e0 + e1 + e2 + e3;
        float sm[4] = { e0 / s, e1 / s, e2 / s, e3 / s };
        #pragma unroll
        for (int i = 0; i < 4; ++i) {
            const int jn = (i + 3) & 3, jp = (i + 1) & 3;
            float inv = 1.0f / fmaxf(sm[jn] + sm[jp], 1e-6f);
            #pragma unroll
            for (int j = 0; j < 4; ++j) {
                float adj = (j == jn || j == jp) ? 1.0f : 0.0f;
                ang[i][j] = sm[j] * adj * inv;
            }
        }
    }
    float rad[2][2];
    {
        float m = fmaxf(rlog[0], rlog[1]);
        float f0 = __expf(rlog[0] - m), f1 = __expf(rlog[1] - m);
        float fs = f0 + f1;
        float sm0 = f0 / fs, sm1 = f1 / fs;
        rad[0][0] = 0.0f; rad[0][1] = sm1 / fmaxf(sm1, 1e-6f);
        rad[1][1] = 0.0f; rad[1][0] = sm0 / fmaxf(sm0, 1e-6f);
    }

    const float4 xv = *reinterpret_cast<const float4*>(x + (size_t)b * 60 + 56);
    float zt[24];
    #pragma unroll
    for (int j = 0; j < 24; ++j) {
        float a = eb1[j];
        a += xv.x * ew1[j];
        a += xv.y * ew1[24 + j];
        a += xv.z * ew1[48 + j];
        a += xv.w * ew1[72 + j];
        zt[j] = fast_tanh(a);
    }
    float z0 = eb3[0], z1 = eb3[1], z2 = eb3[2];
    #pragma unroll
    for (int j = 0; j < 24; ++j) {
        float a = eb2[j];
        #pragma unroll
        for (int k = 0; k < 24; ++k) a += zt[k] * ew2[k * 24 + j];
        const float z2t = fast_tanh(a);
        z0 += z2t * ew3[j * 3 + 0];
        z1 += z2t * ew3[j * 3 + 1];
        z2 += z2t * ew3[j * 3 + 2];
    }

    const float r = 1.0f / (1.0f + __expf(-z0));
    const float p = (z1 + PI_F) / (2.0f * PI_F) * 4.0f;
    const float r0f = truncf(r), p0f = truncf(p);
    const float dr = r - r0f, dp = p - p0f;
    const int r0i = (int)r0f, p0i = (int)p0f;
    const float w0c = (1.0f - dr) * (1.0f - dp);
    const float w1c = (1.0f - dr) * dp;
    const float w2c = dr * (1.0f - dp);
    const float w3c = dr * dp;
    const int ri0 = min(r0i, 1);
    const int ri2 = min(r0i + 1, 1);
    const int pi0 = p0i & 3;
    const int pi1 = (p0i + 1) & 3;
    const int c0 = ri0 * 4 + pi0, c1 = ri0 * 4 + pi1;
    const int c2 = ri2 * 4 + pi0, c3 = ri2 * 4 + pi1;

    float cnt[8], wsum[8];
    #pragma unroll
    for (int n = 0; n < 8; ++n) {
        float cm = 0.0f, cw = 0.0f;
        if (c0 == n && w0c > 0.0f) { cm += 1.0f; cw += w0c; }
        if (c1 == n && w1c > 0.0f) { cm += 1.0f; cw += w1c; }
        if (c2 == n && w2c > 0.0f) { cm += 1.0f; cw += w2c; }
        if (c3 == n && w3c > 0.0f) { cm += 1.0f; cw += w3c; }
        cnt[n] = cm; wsum[n] = cw;
    }
    float mc[8], mw[8];
    #pragma unroll
    for (int n = 0; n < 8; ++n) {
        float ac = cnt[n], aw = wsum[n];
        #pragma unroll
        for (int j = 0; j < 4; ++j) {
            const float g = ang[n >> 1][j];
            ac += g * cnt[2 * j + (n & 1)];
            aw += g * wsum[2 * j + (n & 1)];
        }
        #pragma unroll
        for (int j = 0; j < 2; ++j) {
            const float g = rad[n >> 2][j];
            ac += g * cnt[4 * j + (n & 3)];
            aw += g * wsum[4 * j + (n & 3)];
        }
        mc[n] = ac; mw[n] = aw;
    }

    float t[24];
    #pragma unroll
    for (int j = 0; j < 24; ++j) t[j] = rb1[j];
    #pragma unroll
    for (int n = 0; n < 8; ++n) {
        const float f0 = mc[n] * z0, f1 = mc[n] * z1, f2 = mc[n] * z2;
        float ho[12];
        #pragma unroll
        for (int d = 0; d < 12; ++d) ho[d] = nb2[d];
        #pragma unroll
        for (int j = 0; j < 24; ++j) {
            const float hj = fast_tanh(nb1[j] + f0 * nw1[j] + f1 * nw1[24 + j]
                                       + f2 * nw1[48 + j] + mw[n] * nw1[72 + j]);
            #pragma unroll
            for (int d = 0; d < 12; ++d) ho[d] += hj * nw2[j * 12 + d];
        }
        #pragma unroll
        for (int d = 0; d < 12; ++d) {
            const int rbase = (n * 12 + d) * 24;
            #pragma unroll
            for (int j2 = 0; j2 < 24; ++j2) t[j2] += ho[d] * rw1[rbase + j2];
        }
    }

    float o0 = rb2[0], o1 = rb2[1], o2 = rb2[2], o3 = rb2[3];
    #pragma unroll
    for (int j = 0; j < 24; ++j) {
        const float tt = fast_tanh(t[j]);
        o0 += tt * rw2[j * 4 + 0];
        o1 += tt * rw2[j * 4 + 1];
        o2 += tt * rw2[j * 4 + 2];
        o3 += tt * rw2[j * 4 + 3];
    }
    float4 ov; ov.x = o0; ov.y = o1; ov.z = o2; ov.w = o3;
    *reinterpret_cast<float4*>(out + (size_t)b * 4) = ov;
}

extern "C" void kernel_launch(void* const* d_in, const int* in_sizes, int n_in,
                              void* d_out, int out_size, void* d_ws, size_t ws_size,
                              hipStream_t stream) {
    const float* x    = (const float*)d_in[0];
    const float* ew1  = (const float*)d_in[1];
    const float* eb1  = (const float*)d_in[2];
    const float* ew2  = (const float*)d_in[3];
    const float* eb2  = (const float*)d_in[4];
    const float* ew3  = (const float*)d_in[5];
    const float* eb3  = (const float*)d_in[6];
    const float* nw1  = (const float*)d_in[7];
    const float* nb1  = (const float*)d_in[8];
    const float* nw2  = (const float*)d_in[9];
    const float* nb2  = (const float*)d_in[10];
    const float* alog = (const float*)d_in[11];
    const float* rlog = (const float*)d_in[12];
    const float* rw1  = (const float*)d_in[13];
    const float* rb1  = (const float*)d_in[14];
    const float* rw2  = (const float*)d_in[15];
    const float* rb2  = (const float*)d_in[16];
    float* out = (float*)d_out;

    const int B = in_sizes[0] / 60;   // x is (B, 15, 4)
    const size_t ws_needed = ((size_t)B * 20 + 4632) * sizeof(float);

    if (ws_size >= ws_needed) {
        float* ws = (float*)d_ws;
        const int nb1b = (B + 255) / 256;
        const int g1 = nb1b + 19;                 // + setup blocks (4632 entries)
        topo_k1<<<g1, 256, 0, stream>>>(x, ew1, eb1, ew2, eb2, ew3, eb3,
                                        alog, rlog, nw2, nb2, rw1, rb1, ws, B);
        const long long nP = ((long long)B + 1) / 2;
        const long long tot2 = nP * 8;
        const int g2 = (int)((tot2 + 255) / 256);
        topo_k2<<<g2, 256, 0, stream>>>(ws, nw1, nb1, rw2, rb2, out, B);
    } else {
        const int g = (B + 255) / 256;
        topo_fused<<<g, 256, 0, stream>>>(
            x, ew1, eb1, ew2, eb2, ew3, eb3, nw1, nb1, nw2, nb2,
            alog, rlog, rw1, rb1, rw2, rb2, out, B);
    }
}